// Round 2
// baseline (5948.254 us; speedup 1.0000x reference)
//
#include <hip/hip_runtime.h>
#include <hip/hip_bf16.h>

static constexpr int N_NODES = 100000;
static constexpr int N_EDGES = 3200000;
static constexpr int IN_CH = 512;
static constexpr int H = 16;
static constexpr int TB = 256;

// deg[i] = 1.0 (self-loop) — deg lives in disq buffer, rsqrt'd in place later
__global__ void k_fill1(float* __restrict__ p) {
  int i = blockIdx.x * blockDim.x + threadIdx.x;
  if (i < N_NODES) p[i] = 1.0f;
}

// deg[dst] += 1 per edge (edge_index arrives as int32 per harness contract)
__global__ void k_count(const int* __restrict__ ei, float* __restrict__ deg) {
  int e = blockIdx.x * blockDim.x + threadIdx.x;
  if (e < N_EDGES) {
    int d = ei[N_EDGES + e];
    atomicAdd(deg + d, 1.0f);
  }
}

// disq = rsqrt(deg), in place
__global__ void k_rsq(float* __restrict__ p) {
  int i = blockIdx.x * blockDim.x + threadIdx.x;
  if (i < N_NODES) p[i] = 1.0f / sqrtf(p[i]);
}

// h = X (N x 512) @ W (512 x 16). Thread per row; W accesses are wave-uniform -> scalar loads.
__global__ void k_gemm1(const float* __restrict__ x, const float* __restrict__ W,
                        float* __restrict__ h) {
  int r = blockIdx.x * blockDim.x + threadIdx.x;
  if (r >= N_NODES) return;
  const float4* xr = (const float4*)(x + (size_t)r * IN_CH);
  float acc[H];
#pragma unroll
  for (int c = 0; c < H; c++) acc[c] = 0.f;
  for (int k4 = 0; k4 < IN_CH / 4; k4++) {
    float4 xv = xr[k4];
    const float* wr = W + k4 * 4 * H;
    float xs[4] = {xv.x, xv.y, xv.z, xv.w};
#pragma unroll
    for (int j = 0; j < 4; j++) {
#pragma unroll
      for (int c = 0; c < H; c++) acc[c] = fmaf(xs[j], wr[j * H + c], acc[c]);
    }
  }
  float4* hp = (float4*)(h + (size_t)r * H);
  hp[0] = make_float4(acc[0], acc[1], acc[2], acc[3]);
  hp[1] = make_float4(acc[4], acc[5], acc[6], acc[7]);
  hp[2] = make_float4(acc[8], acc[9], acc[10], acc[11]);
  hp[3] = make_float4(acc[12], acc[13], acc[14], acc[15]);
}

// agg[i][:] = h[i][:] * disq[i]^2 + b[:]  (self-loop term + bias init; atomics add on top)
__global__ void k_self16(const float* __restrict__ h, const float* __restrict__ disq,
                         const float* __restrict__ b, float* __restrict__ agg) {
  int i = blockIdx.x * blockDim.x + threadIdx.x;
  if (i >= N_NODES) return;
  float s = disq[i] * disq[i];
  const float4* hp = (const float4*)(h + (size_t)i * H);
  float4* ap = (float4*)(agg + (size_t)i * H);
  const float4* bp = (const float4*)b;
#pragma unroll
  for (int q = 0; q < 4; q++) {
    float4 hv = hp[q];
    float4 bv = bp[q];
    ap[q] = make_float4(fmaf(hv.x, s, bv.x), fmaf(hv.y, s, bv.y),
                        fmaf(hv.z, s, bv.z), fmaf(hv.w, s, bv.w));
  }
}

// agg[dst][:] += h[src][:] * disq[src]*disq[dst]
__global__ void k_scatter16(const int* __restrict__ ei, const float* __restrict__ disq,
                            const float* __restrict__ h, float* __restrict__ agg) {
  int e = blockIdx.x * blockDim.x + threadIdx.x;
  if (e >= N_EDGES) return;
  int s = ei[e];
  int d = ei[N_EDGES + e];
  float w = disq[s] * disq[d];
  const float4* hp = (const float4*)(h + (size_t)s * H);
  float* ap = agg + (size_t)d * H;
#pragma unroll
  for (int q = 0; q < 4; q++) {
    float4 hv = hp[q];
    atomicAdd(ap + 4 * q + 0, hv.x * w);
    atomicAdd(ap + 4 * q + 1, hv.y * w);
    atomicAdd(ap + 4 * q + 2, hv.z * w);
    atomicAdd(ap + 4 * q + 3, hv.w * w);
  }
}

// h = relu(agg) @ W (16x16); relu fused on load
__global__ void k_gemm16(const float* __restrict__ agg, const float* __restrict__ W,
                         float* __restrict__ h) {
  int r = blockIdx.x * blockDim.x + threadIdx.x;
  if (r >= N_NODES) return;
  const float4* ap = (const float4*)(agg + (size_t)r * H);
  float v[H];
#pragma unroll
  for (int q = 0; q < 4; q++) {
    float4 t = ap[q];
    v[4 * q + 0] = fmaxf(t.x, 0.f);
    v[4 * q + 1] = fmaxf(t.y, 0.f);
    v[4 * q + 2] = fmaxf(t.z, 0.f);
    v[4 * q + 3] = fmaxf(t.w, 0.f);
  }
  float acc[H];
#pragma unroll
  for (int c = 0; c < H; c++) acc[c] = 0.f;
#pragma unroll
  for (int k = 0; k < H; k++) {
#pragma unroll
    for (int c = 0; c < H; c++) acc[c] = fmaf(v[k], W[k * H + c], acc[c]);
  }
  float4* hp = (float4*)(h + (size_t)r * H);
  hp[0] = make_float4(acc[0], acc[1], acc[2], acc[3]);
  hp[1] = make_float4(acc[4], acc[5], acc[6], acc[7]);
  hp[2] = make_float4(acc[8], acc[9], acc[10], acc[11]);
  hp[3] = make_float4(acc[12], acc[13], acc[14], acc[15]);
}

// h3 = relu(agg2) @ W3 (16x1)
__global__ void k_gemm_last(const float* __restrict__ agg, const float* __restrict__ W,
                            float* __restrict__ h3) {
  int r = blockIdx.x * blockDim.x + threadIdx.x;
  if (r >= N_NODES) return;
  const float4* ap = (const float4*)(agg + (size_t)r * H);
  float acc = 0.f;
#pragma unroll
  for (int q = 0; q < 4; q++) {
    float4 t = ap[q];
    acc = fmaf(fmaxf(t.x, 0.f), W[4 * q + 0], acc);
    acc = fmaf(fmaxf(t.y, 0.f), W[4 * q + 1], acc);
    acc = fmaf(fmaxf(t.z, 0.f), W[4 * q + 2], acc);
    acc = fmaf(fmaxf(t.w, 0.f), W[4 * q + 3], acc);
  }
  h3[r] = acc;
}

// out[i] = h3[i]*disq[i]^2 + b3
__global__ void k_self1(const float* __restrict__ h3, const float* __restrict__ disq,
                        const float* __restrict__ b, float* __restrict__ out) {
  int i = blockIdx.x * blockDim.x + threadIdx.x;
  if (i < N_NODES) out[i] = fmaf(h3[i], disq[i] * disq[i], b[0]);
}

__global__ void k_scatter1(const int* __restrict__ ei, const float* __restrict__ disq,
                           const float* __restrict__ h3, float* __restrict__ out) {
  int e = blockIdx.x * blockDim.x + threadIdx.x;
  if (e < N_EDGES) {
    int s = ei[e];
    int d = ei[N_EDGES + e];
    atomicAdd(out + d, h3[s] * disq[s] * disq[d]);
  }
}

extern "C" void kernel_launch(void* const* d_in, const int* in_sizes, int n_in,
                              void* d_out, int out_size, void* d_ws, size_t ws_size,
                              hipStream_t stream) {
  const float* x = (const float*)d_in[0];
  const int* ei = (const int*)d_in[1];  // harness delivers integer inputs as int32
  const float* W1 = (const float*)d_in[2];
  const float* b1 = (const float*)d_in[3];
  const float* W2 = (const float*)d_in[4];
  const float* b2 = (const float*)d_in[5];
  const float* W3 = (const float*)d_in[6];
  const float* b3 = (const float*)d_in[7];
  float* out = (float*)d_out;

  // Workspace: disq[N] | h[N*16] | agg[N*16]  = 13.2 MB total
  float* ws = (float*)d_ws;
  float* disq = ws;                 // N (holds deg, then rsqrt in place)
  float* h = disq + N_NODES;        // N*16 (h1, then h2 in place, then h3 in first N)
  float* agg = h + N_NODES * H;     // N*16 (agg1, then agg2)
  float* h3 = h;                    // reuse: h2 dead once agg2 built

  int gN = (N_NODES + TB - 1) / TB;
  int gE = (N_EDGES + TB - 1) / TB;

  k_fill1<<<gN, TB, 0, stream>>>(disq);
  k_count<<<gE, TB, 0, stream>>>(ei, disq);
  k_rsq<<<gN, TB, 0, stream>>>(disq);

  // Layer 1
  k_gemm1<<<gN, TB, 0, stream>>>(x, W1, h);
  k_self16<<<gN, TB, 0, stream>>>(h, disq, b1, agg);
  k_scatter16<<<gE, TB, 0, stream>>>(ei, disq, h, agg);

  // Layer 2 (relu fused into gemm16 load); h overwritten row-wise from agg
  k_gemm16<<<gN, TB, 0, stream>>>(agg, W2, h);
  k_self16<<<gN, TB, 0, stream>>>(h, disq, b2, agg);
  k_scatter16<<<gE, TB, 0, stream>>>(ei, disq, h, agg);

  // Layer 3 (relu fused into gemm_last load)
  k_gemm_last<<<gN, TB, 0, stream>>>(agg, W3, h3);
  k_self1<<<gN, TB, 0, stream>>>(h3, disq, b3, out);
  k_scatter1<<<gE, TB, 0, stream>>>(ei, disq, h3, out);
}

// Round 3
// 971.791 us; speedup vs baseline: 6.1209x; 6.1209x over previous
//
#include <hip/hip_runtime.h>
#include <hip/hip_bf16.h>

static constexpr int N_NODES = 100000;
static constexpr int N_EDGES = 3200000;
static constexpr int IN_CH = 512;
static constexpr int H = 16;
static constexpr int TB = 256;
static constexpr int SCAN_CHUNK = 1024;
static constexpr int NB_SCAN = (N_NODES + SCAN_CHUNK - 1) / SCAN_CHUNK;  // 98

__global__ void k_zero(int* __restrict__ p, int n) {
  int i = blockIdx.x * blockDim.x + threadIdx.x;
  if (i < n) p[i] = 0;
}

// cnt[dst]++ per edge (edge_index delivered as int32)
__global__ void k_hist(const int* __restrict__ ei, int* __restrict__ cnt) {
  int e = blockIdx.x * blockDim.x + threadIdx.x;
  if (e < N_EDGES) atomicAdd(cnt + ei[N_EDGES + e], 1);
}

// Block-level inclusive scan of cnt into rs[1..N]; rs[0]=0; per-block totals to bsum.
__global__ void k_scan_block(const int* __restrict__ cnt, int* __restrict__ rs,
                             int* __restrict__ bsum) {
  __shared__ int lds[TB];
  int b = blockIdx.x;
  int base = b * SCAN_CHUNK;
  int t = threadIdx.x;
  int v[4];
  int s = 0;
#pragma unroll
  for (int j = 0; j < 4; j++) {
    int idx = base + t * 4 + j;
    v[j] = (idx < N_NODES) ? cnt[idx] : 0;
    s += v[j];
  }
  lds[t] = s;
  __syncthreads();
  for (int off = 1; off < TB; off <<= 1) {
    int x = (t >= off) ? lds[t - off] : 0;
    __syncthreads();
    lds[t] += x;
    __syncthreads();
  }
  int excl = (t == 0) ? 0 : lds[t - 1];
  if (t == TB - 1) bsum[b] = lds[TB - 1];
  int run = excl;
#pragma unroll
  for (int j = 0; j < 4; j++) {
    int idx = base + t * 4 + j;
    run += v[j];
    if (idx < N_NODES) rs[idx + 1] = run;
  }
  if (b == 0 && t == 0) rs[0] = 0;
}

// Exclusive scan of 98 block sums (tiny; serial on one thread)
__global__ void k_scan_bsum(int* __restrict__ bsum) {
  if (threadIdx.x == 0 && blockIdx.x == 0) {
    int acc = 0;
    for (int i = 0; i < NB_SCAN; i++) { int c = bsum[i]; bsum[i] = acc; acc += c; }
  }
}

__global__ void k_scan_add(int* __restrict__ rs, const int* __restrict__ bsum) {
  int i = blockIdx.x * blockDim.x + threadIdx.x;
  if (i < N_NODES) rs[i + 1] += bsum[i / SCAN_CHUNK];
}

// disq[i] = 1/sqrt(cnt[i] + 1)  (A + I degree)
__global__ void k_rsq(const int* __restrict__ cnt, float* __restrict__ disq) {
  int i = blockIdx.x * blockDim.x + threadIdx.x;
  if (i < N_NODES) disq[i] = 1.0f / sqrtf((float)cnt[i] + 1.0f);
}

// cursor init: cur[i] = rs[i]  (cur aliases the cnt buffer; cnt no longer needed)
__global__ void k_cursor(const int* __restrict__ rs, int* __restrict__ cur) {
  int i = blockIdx.x * blockDim.x + threadIdx.x;
  if (i < N_NODES) cur[i] = rs[i];
}

// csr[slot] = src, grouped by dst
__global__ void k_csr_fill(const int* __restrict__ ei, int* __restrict__ cur,
                           int* __restrict__ csr) {
  int e = blockIdx.x * blockDim.x + threadIdx.x;
  if (e < N_EDGES) {
    int s = ei[e];
    int d = ei[N_EDGES + e];
    int slot = atomicAdd(cur + d, 1);
    csr[slot] = s;
  }
}

// h = X (N x 512) @ W (512 x 16). Thread per row; W wave-uniform -> scalar loads.
__global__ void k_gemm1(const float* __restrict__ x, const float* __restrict__ W,
                        float* __restrict__ h) {
  int r = blockIdx.x * blockDim.x + threadIdx.x;
  if (r >= N_NODES) return;
  const float4* xr = (const float4*)(x + (size_t)r * IN_CH);
  float acc[H];
#pragma unroll
  for (int c = 0; c < H; c++) acc[c] = 0.f;
  for (int k4 = 0; k4 < IN_CH / 4; k4++) {
    float4 xv = xr[k4];
    const float* wr = W + k4 * 4 * H;
    float xs[4] = {xv.x, xv.y, xv.z, xv.w};
#pragma unroll
    for (int j = 0; j < 4; j++) {
#pragma unroll
      for (int c = 0; c < H; c++) acc[c] = fmaf(xs[j], wr[j * H + c], acc[c]);
    }
  }
  float4* hp = (float4*)(h + (size_t)r * H);
  hp[0] = make_float4(acc[0], acc[1], acc[2], acc[3]);
  hp[1] = make_float4(acc[4], acc[5], acc[6], acc[7]);
  hp[2] = make_float4(acc[8], acc[9], acc[10], acc[11]);
  hp[3] = make_float4(acc[12], acc[13], acc[14], acc[15]);
}

// agg[node][lane] = sum_{e in in(node)} h[src][lane]*disq[src]*disq[node]
//                 + h[node][lane]*disq[node]^2 + b[lane]
// 16 lanes per node, lane = channel.
__global__ void k_gather16(const int* __restrict__ rs, const int* __restrict__ csr,
                           const float* __restrict__ disq, const float* __restrict__ h,
                           const float* __restrict__ b, float* __restrict__ agg) {
  int tid = blockIdx.x * blockDim.x + threadIdx.x;
  int node = tid >> 4;
  int lane = tid & 15;
  if (node >= N_NODES) return;
  int beg = rs[node];
  int end = rs[node + 1];
  float dn = disq[node];
  float acc = 0.f;
  for (int j = beg; j < end; j++) {
    int s = csr[j];
    acc = fmaf(h[(size_t)s * H + lane], disq[s], acc);
  }
  float r = fmaf(acc, dn, b[lane]);
  r = fmaf(h[(size_t)node * H + lane] * dn, dn, r);
  agg[(size_t)node * H + lane] = r;
}

// h = relu(agg) @ W (16x16); relu fused on load
__global__ void k_gemm16(const float* __restrict__ agg, const float* __restrict__ W,
                         float* __restrict__ h) {
  int r = blockIdx.x * blockDim.x + threadIdx.x;
  if (r >= N_NODES) return;
  const float4* ap = (const float4*)(agg + (size_t)r * H);
  float v[H];
#pragma unroll
  for (int q = 0; q < 4; q++) {
    float4 t = ap[q];
    v[4 * q + 0] = fmaxf(t.x, 0.f);
    v[4 * q + 1] = fmaxf(t.y, 0.f);
    v[4 * q + 2] = fmaxf(t.z, 0.f);
    v[4 * q + 3] = fmaxf(t.w, 0.f);
  }
  float acc[H];
#pragma unroll
  for (int c = 0; c < H; c++) acc[c] = 0.f;
#pragma unroll
  for (int k = 0; k < H; k++) {
#pragma unroll
    for (int c = 0; c < H; c++) acc[c] = fmaf(v[k], W[k * H + c], acc[c]);
  }
  float4* hp = (float4*)(h + (size_t)r * H);
  hp[0] = make_float4(acc[0], acc[1], acc[2], acc[3]);
  hp[1] = make_float4(acc[4], acc[5], acc[6], acc[7]);
  hp[2] = make_float4(acc[8], acc[9], acc[10], acc[11]);
  hp[3] = make_float4(acc[12], acc[13], acc[14], acc[15]);
}

// h3 = relu(agg2) @ W3 (16x1)
__global__ void k_gemm_last(const float* __restrict__ agg, const float* __restrict__ W,
                            float* __restrict__ h3) {
  int r = blockIdx.x * blockDim.x + threadIdx.x;
  if (r >= N_NODES) return;
  const float4* ap = (const float4*)(agg + (size_t)r * H);
  float acc = 0.f;
#pragma unroll
  for (int q = 0; q < 4; q++) {
    float4 t = ap[q];
    acc = fmaf(fmaxf(t.x, 0.f), W[4 * q + 0], acc);
    acc = fmaf(fmaxf(t.y, 0.f), W[4 * q + 1], acc);
    acc = fmaf(fmaxf(t.z, 0.f), W[4 * q + 2], acc);
    acc = fmaf(fmaxf(t.w, 0.f), W[4 * q + 3], acc);
  }
  h3[r] = acc;
}

// out[node] = (sum_e h3[src]*disq[src])*disq[node] + h3[node]*disq[node]^2 + b3
// 16 lanes per node, lane-parallel over edges, shfl reduce.
__global__ void k_gather1(const int* __restrict__ rs, const int* __restrict__ csr,
                          const float* __restrict__ disq, const float* __restrict__ h3,
                          const float* __restrict__ b, float* __restrict__ out) {
  int tid = blockIdx.x * blockDim.x + threadIdx.x;
  int node = tid >> 4;
  int lane = tid & 15;
  if (node >= N_NODES) return;
  int beg = rs[node];
  int end = rs[node + 1];
  float acc = 0.f;
  for (int j = beg + lane; j < end; j += 16) {
    int s = csr[j];
    acc = fmaf(h3[s], disq[s], acc);
  }
#pragma unroll
  for (int off = 8; off >= 1; off >>= 1) acc += __shfl_xor(acc, off);
  if (lane == 0) {
    float dn = disq[node];
    float r = fmaf(acc, dn, b[0]);
    out[node] = fmaf(h3[node] * dn, dn, r);
  }
}

extern "C" void kernel_launch(void* const* d_in, const int* in_sizes, int n_in,
                              void* d_out, int out_size, void* d_ws, size_t ws_size,
                              hipStream_t stream) {
  const float* x = (const float*)d_in[0];
  const int* ei = (const int*)d_in[1];
  const float* W1 = (const float*)d_in[2];
  const float* b1 = (const float*)d_in[3];
  const float* W2 = (const float*)d_in[4];
  const float* b2 = (const float*)d_in[5];
  const float* W3 = (const float*)d_in[6];
  const float* b3 = (const float*)d_in[7];
  float* out = (float*)d_out;

  // Workspace layout (~26.8 MB):
  int* cnt = (int*)d_ws;                  // N   (histogram, then reused as cursor)
  int* rs = cnt + N_NODES;                // N+1 (row starts)
  int* csr = rs + N_NODES + 1;            // E   (src indices grouped by dst)
  int* bsum = csr + N_EDGES;              // NB_SCAN
  float* disq = (float*)(bsum + NB_SCAN); // N
  float* h = disq + N_NODES;              // 16N
  float* agg = h + (size_t)N_NODES * H;   // 16N
  float* h3 = h;                          // reuse

  int gN = (N_NODES + TB - 1) / TB;
  int gE = (N_EDGES + TB - 1) / TB;
  int gN16 = ((N_NODES * 16) + TB - 1) / TB;

  // CSR build
  k_zero<<<gN, TB, 0, stream>>>(cnt, N_NODES);
  k_hist<<<gE, TB, 0, stream>>>(ei, cnt);
  k_scan_block<<<NB_SCAN, TB, 0, stream>>>(cnt, rs, bsum);
  k_scan_bsum<<<1, 64, 0, stream>>>(bsum);
  k_scan_add<<<gN, TB, 0, stream>>>(rs, bsum);
  k_rsq<<<gN, TB, 0, stream>>>(cnt, disq);
  k_cursor<<<gN, TB, 0, stream>>>(rs, cnt);
  k_csr_fill<<<gE, TB, 0, stream>>>(ei, cnt, csr);

  // Layer 1
  k_gemm1<<<gN, TB, 0, stream>>>(x, W1, h);
  k_gather16<<<gN16, TB, 0, stream>>>(rs, csr, disq, h, b1, agg);
  // Layer 2
  k_gemm16<<<gN, TB, 0, stream>>>(agg, W2, h);
  k_gather16<<<gN16, TB, 0, stream>>>(rs, csr, disq, h, b2, agg);
  // Layer 3
  k_gemm_last<<<gN, TB, 0, stream>>>(agg, W3, h3);
  k_gather1<<<gN16, TB, 0, stream>>>(rs, csr, disq, h3, b3, out);
}